// Round 1
// baseline (712.648 us; speedup 1.0000x reference)
//
#include <hip/hip_runtime.h>
#include <hip/hip_bf16.h>

#define NN 100000
#define NE 1600000
#define IN_F 128
#define OUT_F 64

// order-preserving float->uint key (0 == key(-NaN) == minimum, so memset-0 init works)
__device__ __forceinline__ unsigned fkey(float f) {
  unsigned u = __float_as_uint(f);
  return (u & 0x80000000u) ? ~u : (u | 0x80000000u);
}
__device__ __forceinline__ float funkey(unsigned k) {
  return (k & 0x80000000u) ? __uint_as_float(k ^ 0x80000000u) : __uint_as_float(~k);
}

// Kernel 1: xv = x@Wv + bv ; el = xv.wq + bq ; er = xv.wk + bk
// one wave per node (4 nodes per wave via rep loop), lane = output feature
__global__ __launch_bounds__(256) void node_transform(
    const float* __restrict__ x, const float* __restrict__ Wv,
    const float* __restrict__ bv, const float* __restrict__ wq,
    const float* __restrict__ bq, const float* __restrict__ wk,
    const float* __restrict__ bk,
    float* __restrict__ xv, float* __restrict__ el, float* __restrict__ er) {
  __shared__ float sW[IN_F * OUT_F];
  __shared__ float svec[2 * OUT_F + 2];
  for (int i = threadIdx.x; i < IN_F * OUT_F; i += 256) sW[i] = Wv[i];
  if (threadIdx.x < OUT_F) {
    svec[threadIdx.x] = wq[threadIdx.x];
    svec[OUT_F + threadIdx.x] = wk[threadIdx.x];
  }
  if (threadIdx.x == 0) { svec[128] = bq[0]; svec[129] = bk[0]; }
  __syncthreads();

  const int wave = threadIdx.x >> 6, lane = threadIdx.x & 63;
  const float bvl = bv[lane];
  const float wql = svec[lane], wkl = svec[OUT_F + lane];

  for (int rep = 0; rep < 4; ++rep) {
    const int node = blockIdx.x * 16 + wave * 4 + rep;
    if (node >= NN) return;
    const float* xr = x + (size_t)node * IN_F;
    const float xa = xr[lane];
    const float xb = xr[64 + lane];
    float acc = bvl;
#pragma unroll
    for (int k = 0; k < 64; ++k) {
      acc += __shfl(xa, k) * sW[k * 64 + lane];
      acc += __shfl(xb, k) * sW[(k + 64) * 64 + lane];
    }
    xv[(size_t)node * 64 + lane] = acc;
    float pq = acc * wql;
    float pk = acc * wkl;
#pragma unroll
    for (int off = 32; off; off >>= 1) {
      pq += __shfl_xor(pq, off);
      pk += __shfl_xor(pk, off);
    }
    if (lane == 0) {
      el[node] = pq + svec[128];
      er[node] = pk + svec[129];
    }
  }
}

// Kernel 2: e = leaky_relu(el[src]+er[dst]); segment max via atomic uint-key max
__global__ __launch_bounds__(256) void edge_score(
    const float* __restrict__ el, const float* __restrict__ er,
    const int* __restrict__ src, const int* __restrict__ dst,
    float* __restrict__ e_out, unsigned* __restrict__ emaxk) {
  const int i = blockIdx.x * 256 + threadIdx.x;
  if (i >= NE) return;
  const int s = src[i], d = dst[i];
  float e = el[s] + er[d];
  e = e > 0.f ? e : 0.2f * e;
  e_out[i] = e;
  atomicMax(&emaxk[d], fkey(e));
}

// Kernel 3: ex = exp(e - max[dst]); denom[dst] += ex
__global__ __launch_bounds__(256) void edge_exp(
    const float* __restrict__ e_in, const unsigned* __restrict__ emaxk,
    const int* __restrict__ dst,
    float* __restrict__ ex, float* __restrict__ denom) {
  const int i = blockIdx.x * 256 + threadIdx.x;
  if (i >= NE) return;
  const int d = dst[i];
  const float m = funkey(emaxk[d]);
  const float v = expf(e_in[i] - m);
  ex[i] = v;
  unsafeAtomicAdd(&denom[d], v);
}

// Kernel 4: out[dst] += xv[src] * (ex/denom[dst]) — one wave per edge, lane = feature
__global__ __launch_bounds__(256) void aggregate(
    const float* __restrict__ xv, const float* __restrict__ ex,
    const float* __restrict__ denom,
    const int* __restrict__ src, const int* __restrict__ dst,
    float* __restrict__ out) {
  const int edge = (int)((blockIdx.x * 256 + threadIdx.x) >> 6);
  const int lane = threadIdx.x & 63;
  if (edge >= NE) return;
  const int s = src[edge], d = dst[edge];
  const float attn = ex[edge] / denom[d];
  const float v = xv[(size_t)s * 64 + lane];
  unsafeAtomicAdd(&out[(size_t)d * 64 + lane], v * attn);
}

extern "C" void kernel_launch(void* const* d_in, const int* in_sizes, int n_in,
                              void* d_out, int out_size, void* d_ws, size_t ws_size,
                              hipStream_t stream) {
  const float* x  = (const float*)d_in[0];
  const float* Wv = (const float*)d_in[1];
  const float* bv = (const float*)d_in[2];
  const float* wq = (const float*)d_in[3];
  const float* bq = (const float*)d_in[4];
  const float* wk = (const float*)d_in[5];
  const float* bk = (const float*)d_in[6];
  const int* src  = (const int*)d_in[7];
  const int* dst  = (const int*)d_in[8];
  float* out = (float*)d_out;

  // workspace layout (fp32 words): xv[NN*64] el[NN] er[NN] emaxk[NN] denom[NN] e[NE] ex[NE]
  float* xv = (float*)d_ws;
  float* el = xv + (size_t)NN * 64;
  float* er = el + NN;
  unsigned* emaxk = (unsigned*)(er + NN);
  float* denom = (float*)(emaxk + NN);
  float* e_arr = denom + NN;
  float* ex = e_arr + NE;

  hipMemsetAsync(out, 0, (size_t)out_size * sizeof(float), stream);
  hipMemsetAsync(emaxk, 0, (size_t)NN * 2 * sizeof(unsigned), stream);  // emaxk + denom

  node_transform<<<NN / 16, 256, 0, stream>>>(x, Wv, bv, wq, bq, wk, bk, xv, el, er);
  edge_score<<<(NE + 255) / 256, 256, 0, stream>>>(el, er, src, dst, e_arr, emaxk);
  edge_exp<<<(NE + 255) / 256, 256, 0, stream>>>(e_arr, emaxk, dst, ex, denom);
  aggregate<<<(NE * 64) / 256, 256, 0, stream>>>(xv, ex, denom, src, dst, out);
}

// Round 2
// 615.265 us; speedup vs baseline: 1.1583x; 1.1583x over previous
//
#include <hip/hip_runtime.h>
#include <hip/hip_bf16.h>

#define NN 100000
#define NE 1600000
#define IN_F 128
#define OUT_F 64

// ---------------- Kernel 1: xv = x@Wv + bv ; el = xv.wq + bq ; er = xv.wk + bk
// one wave per node (4 nodes per wave via rep loop), lane = output feature
__global__ __launch_bounds__(256) void node_transform(
    const float* __restrict__ x, const float* __restrict__ Wv,
    const float* __restrict__ bv, const float* __restrict__ wq,
    const float* __restrict__ bq, const float* __restrict__ wk,
    const float* __restrict__ bk,
    float* __restrict__ xv, float* __restrict__ el, float* __restrict__ er) {
  __shared__ float sW[IN_F * OUT_F];
  __shared__ float svec[2 * OUT_F + 2];
  for (int i = threadIdx.x; i < IN_F * OUT_F; i += 256) sW[i] = Wv[i];
  if (threadIdx.x < OUT_F) {
    svec[threadIdx.x] = wq[threadIdx.x];
    svec[OUT_F + threadIdx.x] = wk[threadIdx.x];
  }
  if (threadIdx.x == 0) { svec[128] = bq[0]; svec[129] = bk[0]; }
  __syncthreads();

  const int wave = threadIdx.x >> 6, lane = threadIdx.x & 63;
  const float bvl = bv[lane];
  const float wql = svec[lane], wkl = svec[OUT_F + lane];

  for (int rep = 0; rep < 4; ++rep) {
    const int node = blockIdx.x * 16 + wave * 4 + rep;
    if (node >= NN) return;
    const float* xr = x + (size_t)node * IN_F;
    const float xa = xr[lane];
    const float xb = xr[64 + lane];
    float acc = bvl;
#pragma unroll
    for (int k = 0; k < 64; ++k) {
      acc += __shfl(xa, k) * sW[k * 64 + lane];
      acc += __shfl(xb, k) * sW[(k + 64) * 64 + lane];
    }
    xv[(size_t)node * 64 + lane] = acc;
    float pq = acc * wql;
    float pk = acc * wkl;
#pragma unroll
    for (int off = 32; off; off >>= 1) {
      pq += __shfl_xor(pq, off);
      pk += __shfl_xor(pk, off);
    }
    if (lane == 0) {
      el[node] = pq + svec[128];
      er[node] = pk + svec[129];
    }
  }
}

// ---------------- Kernel 2: per-dst in-degree histogram
__global__ __launch_bounds__(256) void count_deg(
    const int* __restrict__ dst, int* __restrict__ cnt) {
  const int i = blockIdx.x * 256 + threadIdx.x;
  if (i >= NE) return;
  atomicAdd(&cnt[dst[i]], 1);
}

// ---------------- Kernel 3: exclusive scan of cnt -> off (single block, 1024 thr)
#define SCAN_CH 98  // 1024*98 >= 100000
__global__ __launch_bounds__(1024) void scan_kernel(
    const int* __restrict__ cnt, int* __restrict__ off) {
  __shared__ int part[1024];
  const int t = threadIdx.x;
  const int lo = t * SCAN_CH;
  const int hi = min(lo + SCAN_CH, NN);
  int s = 0;
  for (int i = lo; i < hi; ++i) s += cnt[i];
  part[t] = s;
  __syncthreads();
  for (int o = 1; o < 1024; o <<= 1) {
    int v = (t >= o) ? part[t - o] : 0;
    __syncthreads();
    part[t] += v;
    __syncthreads();
  }
  int run = (t > 0) ? part[t - 1] : 0;
  for (int i = lo; i < hi; ++i) { off[i] = run; run += cnt[i]; }
}

// ---------------- Kernel 4: scatter edges into CSR slots; fuse leaky-relu score
__global__ __launch_bounds__(256) void scatter_edges(
    const float* __restrict__ el, const float* __restrict__ er,
    const int* __restrict__ src, const int* __restrict__ dst,
    const int* __restrict__ off, int* __restrict__ cursor,
    int* __restrict__ csr_src, float* __restrict__ csr_e) {
  const int i = blockIdx.x * 256 + threadIdx.x;
  if (i >= NE) return;
  const int s = src[i], d = dst[i];
  float e = el[s] + er[d];
  e = e > 0.f ? e : 0.2f * e;
  const int pos = atomicAdd(&cursor[d], 1);
  const int idx = off[d] + pos;
  csr_src[idx] = s;
  csr_e[idx] = e;
}

// ---------------- Kernel 5: per-node fused softmax + weighted gather-sum
// one wave per dst node, lane = output feature
__global__ __launch_bounds__(256) void node_aggregate(
    const float* __restrict__ xv, const int* __restrict__ cnt,
    const int* __restrict__ off, const int* __restrict__ csr_src,
    const float* __restrict__ csr_e, float* __restrict__ out) {
  const int wave = threadIdx.x >> 6, lane = threadIdx.x & 63;
  const int node = blockIdx.x * 4 + wave;
  if (node >= NN) return;
  const int deg = cnt[node];
  const int base = off[node];

  // pass A1: max over edge scores (lanes stride over edges)
  float m = -3.0e38f;
  for (int k = lane; k < deg; k += 64) m = fmaxf(m, csr_e[base + k]);
#pragma unroll
  for (int o = 32; o; o >>= 1) m = fmaxf(m, __shfl_xor(m, o));

  // pass A2: denom = sum exp(e - m)
  float ssum = 0.f;
  for (int k = lane; k < deg; k += 64) ssum += __expf(csr_e[base + k] - m);
#pragma unroll
  for (int o = 32; o; o >>= 1) ssum += __shfl_xor(ssum, o);
  const float inv = deg > 0 ? 1.0f / ssum : 0.f;

  // pass B: acc = sum attn_k * xv[src_k][lane]   (serial over edges, lane=feature)
  float acc = 0.f;
  int k = 0;
  for (; k + 2 <= deg; k += 2) {
    const int s0 = csr_src[base + k], s1 = csr_src[base + k + 1];
    const float p0 = __expf(csr_e[base + k] - m) * inv;
    const float p1 = __expf(csr_e[base + k + 1] - m) * inv;
    const float v0 = xv[(size_t)s0 * 64 + lane];
    const float v1 = xv[(size_t)s1 * 64 + lane];
    acc += p0 * v0 + p1 * v1;
  }
  if (k < deg) {
    const int s0 = csr_src[base + k];
    const float p0 = __expf(csr_e[base + k] - m) * inv;
    acc += p0 * xv[(size_t)s0 * 64 + lane];
  }
  out[(size_t)node * 64 + lane] = acc;
}

extern "C" void kernel_launch(void* const* d_in, const int* in_sizes, int n_in,
                              void* d_out, int out_size, void* d_ws, size_t ws_size,
                              hipStream_t stream) {
  const float* x  = (const float*)d_in[0];
  const float* Wv = (const float*)d_in[1];
  const float* bv = (const float*)d_in[2];
  const float* wq = (const float*)d_in[3];
  const float* bq = (const float*)d_in[4];
  const float* wk = (const float*)d_in[5];
  const float* bk = (const float*)d_in[6];
  const int* src  = (const int*)d_in[7];
  const int* dst  = (const int*)d_in[8];
  float* out = (float*)d_out;

  // workspace layout (4-byte words):
  // xv[NN*64] el[NN] er[NN] cnt[NN] cursor[NN] off[NN] csr_src[NE] csr_e[NE]
  float* xv = (float*)d_ws;
  float* el = xv + (size_t)NN * 64;
  float* er = el + NN;
  int* cnt = (int*)(er + NN);
  int* cursor = cnt + NN;          // cnt+cursor adjacent -> one memset
  int* off = cursor + NN;
  int* csr_src = off + NN;
  float* csr_e = (float*)(csr_src + NE);

  hipMemsetAsync(cnt, 0, (size_t)NN * 2 * sizeof(int), stream);  // cnt + cursor

  node_transform<<<NN / 16, 256, 0, stream>>>(x, Wv, bv, wq, bq, wk, bk, xv, el, er);
  count_deg<<<(NE + 255) / 256, 256, 0, stream>>>(dst, cnt);
  scan_kernel<<<1, 1024, 0, stream>>>(cnt, off);
  scatter_edges<<<(NE + 255) / 256, 256, 0, stream>>>(el, er, src, dst, off, cursor,
                                                      csr_src, csr_e);
  node_aggregate<<<(NN + 3) / 4, 256, 0, stream>>>(xv, cnt, off, csr_src, csr_e, out);
}

// Round 3
// 397.293 us; speedup vs baseline: 1.7938x; 1.5486x over previous
//
#include <hip/hip_runtime.h>
#include <hip/hip_bf16.h>

#define NN 100000
#define NE 1600000
#define IN_F 128
#define OUT_F 64

typedef __attribute__((ext_vector_type(8))) short bf16x8;
typedef __attribute__((ext_vector_type(4))) float f32x4;

__device__ __forceinline__ short f2bf(float f) {
  unsigned u = __float_as_uint(f);
  unsigned r = (u + 0x7fffu + ((u >> 16) & 1u)) >> 16;  // RNE
  return (short)r;
}

// ---------------- Kernel 0: wvt[j][k] = bf16(Wv[k][j])  (64 x 128 transposed)
__global__ __launch_bounds__(256) void prep_w(
    const float* __restrict__ Wv, short* __restrict__ wvt) {
  const int i = blockIdx.x * 256 + threadIdx.x;
  if (i >= IN_F * OUT_F) return;
  const int j = i >> 7, k = i & 127;
  wvt[i] = f2bf(Wv[k * OUT_F + j]);
}

// ---------------- Kernel 1: xv = x@Wv + bv ; el = xv.wq + bq ; er = xv.wk + bk
// MFMA 16x16x32 bf16. Block = 4 waves, each wave owns 16 nodes x 64 feats.
__global__ __launch_bounds__(256) void node_transform(
    const float* __restrict__ x, const short* __restrict__ wvt,
    const float* __restrict__ bv, const float* __restrict__ wq,
    const float* __restrict__ bq, const float* __restrict__ wk,
    const float* __restrict__ bk,
    float* __restrict__ xv, float* __restrict__ el, float* __restrict__ er) {
  const int wave = threadIdx.x >> 6, lane = threadIdx.x & 63;
  const int node0 = blockIdx.x * 64 + wave * 16;
  const int j15 = lane & 15, g = lane >> 4;
  const int kb = g * 8;

  // A fragments: lane holds x[node0 + j15][kt*32 + kb .. +8] as bf16
  int row = node0 + j15;
  if (row >= NN) row = NN - 1;
  const float* xr = x + (size_t)row * IN_F;
  bf16x8 a[4];
#pragma unroll
  for (int kt = 0; kt < 4; ++kt) {
    const float4 f0 = *(const float4*)(xr + kt * 32 + kb);
    const float4 f1 = *(const float4*)(xr + kt * 32 + kb + 4);
    bf16x8 t;
    t[0] = f2bf(f0.x); t[1] = f2bf(f0.y); t[2] = f2bf(f0.z); t[3] = f2bf(f0.w);
    t[4] = f2bf(f1.x); t[5] = f2bf(f1.y); t[6] = f2bf(f1.z); t[7] = f2bf(f1.w);
    a[kt] = t;
  }

  // B fragments: lane holds Wv[kt*32 + kb .. +8][nt*16 + j15] = wvt[nt*16+j15][...]
  bf16x8 b[16];
#pragma unroll
  for (int nt = 0; nt < 4; ++nt)
#pragma unroll
    for (int kt = 0; kt < 4; ++kt)
      b[nt * 4 + kt] = *(const bf16x8*)(wvt + (size_t)(nt * 16 + j15) * IN_F + kt * 32 + kb);

  f32x4 acc[4];
#pragma unroll
  for (int nt = 0; nt < 4; ++nt) acc[nt] = (f32x4){0.f, 0.f, 0.f, 0.f};
#pragma unroll
  for (int nt = 0; nt < 4; ++nt)
#pragma unroll
    for (int kt = 0; kt < 4; ++kt)
      acc[nt] = __builtin_amdgcn_mfma_f32_16x16x32_bf16(a[kt], b[nt * 4 + kt], acc[nt], 0, 0, 0);

  // epilogue: bias, store xv, fused el/er
  float bvl[4], wql[4], wkl[4];
#pragma unroll
  for (int nt = 0; nt < 4; ++nt) {
    bvl[nt] = bv[nt * 16 + j15];
    wql[nt] = wq[nt * 16 + j15];
    wkl[nt] = wk[nt * 16 + j15];
  }
  const float bq0 = bq[0], bk0 = bk[0];

#pragma unroll
  for (int r = 0; r < 4; ++r) {
    const int node = node0 + g * 4 + r;
    float pq = 0.f, pk = 0.f;
#pragma unroll
    for (int nt = 0; nt < 4; ++nt) {
      const float v = acc[nt][r] + bvl[nt];
      if (node < NN) xv[(size_t)node * OUT_F + nt * 16 + j15] = v;
      pq += v * wql[nt];
      pk += v * wkl[nt];
    }
#pragma unroll
    for (int o = 1; o < 16; o <<= 1) {
      pq += __shfl_xor(pq, o);
      pk += __shfl_xor(pk, o);
    }
    if (j15 == 0 && node < NN) {
      el[node] = pq + bq0;
      er[node] = pk + bk0;
    }
  }
}

// ---------------- Kernel 2: per-dst in-degree histogram
__global__ __launch_bounds__(256) void count_deg(
    const int* __restrict__ dst, int* __restrict__ cnt) {
  const int i = blockIdx.x * 256 + threadIdx.x;
  if (i >= NE) return;
  atomicAdd(&cnt[dst[i]], 1);
}

// ---------------- Kernel 3: exclusive scan of cnt -> off (single block, 1024 thr)
#define SCAN_CH 98  // 1024*98 >= 100000
__global__ __launch_bounds__(1024) void scan_kernel(
    const int* __restrict__ cnt, int* __restrict__ off) {
  __shared__ int part[1024];
  const int t = threadIdx.x;
  const int lo = t * SCAN_CH;
  const int hi = min(lo + SCAN_CH, NN);
  int s = 0;
  for (int i = lo; i < hi; ++i) s += cnt[i];
  part[t] = s;
  __syncthreads();
  for (int o = 1; o < 1024; o <<= 1) {
    int v = (t >= o) ? part[t - o] : 0;
    __syncthreads();
    part[t] += v;
    __syncthreads();
  }
  int run = (t > 0) ? part[t - 1] : 0;
  for (int i = lo; i < hi; ++i) { off[i] = run; run += cnt[i]; }
}

// ---------------- Kernel 4: scatter edges into CSR slots; fuse leaky-relu score
__global__ __launch_bounds__(256) void scatter_edges(
    const float* __restrict__ el, const float* __restrict__ er,
    const int* __restrict__ src, const int* __restrict__ dst,
    const int* __restrict__ off, int* __restrict__ cursor,
    int* __restrict__ csr_src, float* __restrict__ csr_e) {
  const int i = blockIdx.x * 256 + threadIdx.x;
  if (i >= NE) return;
  const int s = src[i], d = dst[i];
  float e = el[s] + er[d];
  e = e > 0.f ? e : 0.2f * e;
  const int pos = atomicAdd(&cursor[d], 1);
  const int idx = off[d] + pos;
  csr_src[idx] = s;
  csr_e[idx] = e;
}

// ---------------- Kernel 5: per-node fused softmax + weighted gather-sum
// one wave per dst node, lane = output feature; deg<=64 fast path keeps edges in regs
__global__ __launch_bounds__(256) void node_aggregate(
    const float* __restrict__ xv, const int* __restrict__ cnt,
    const int* __restrict__ off, const int* __restrict__ csr_src,
    const float* __restrict__ csr_e, float* __restrict__ out) {
  const int wave = threadIdx.x >> 6, lane = threadIdx.x & 63;
  const int node = blockIdx.x * 4 + wave;
  if (node >= NN) return;
  const int deg = cnt[node];
  const int base = off[node];

  float acc = 0.f;
  if (deg <= 64) {
    const bool valid = lane < deg;
    float e = valid ? csr_e[base + lane] : -3.0e38f;
    int s = valid ? csr_src[base + lane] : 0;
    float m = e;
#pragma unroll
    for (int o = 32; o; o >>= 1) m = fmaxf(m, __shfl_xor(m, o));
    float p = valid ? __expf(e - m) : 0.f;
    float t = p;
#pragma unroll
    for (int o = 32; o; o >>= 1) t += __shfl_xor(t, o);
    p *= (deg > 0) ? (1.0f / t) : 0.f;

    int k = 0;
    for (; k + 4 <= deg; k += 4) {
      const int s0 = __shfl(s, k), s1 = __shfl(s, k + 1);
      const int s2 = __shfl(s, k + 2), s3 = __shfl(s, k + 3);
      const float p0 = __shfl(p, k), p1 = __shfl(p, k + 1);
      const float p2 = __shfl(p, k + 2), p3 = __shfl(p, k + 3);
      const float v0 = xv[(size_t)s0 * OUT_F + lane];
      const float v1 = xv[(size_t)s1 * OUT_F + lane];
      const float v2 = xv[(size_t)s2 * OUT_F + lane];
      const float v3 = xv[(size_t)s3 * OUT_F + lane];
      acc += p0 * v0 + p1 * v1 + p2 * v2 + p3 * v3;
    }
    for (; k < deg; ++k) {
      const int sk = __shfl(s, k);
      const float pk = __shfl(p, k);
      acc += pk * xv[(size_t)sk * OUT_F + lane];
    }
  } else {
    // general fallback (rare): 3-pass over CSR
    float m = -3.0e38f;
    for (int k = lane; k < deg; k += 64) m = fmaxf(m, csr_e[base + k]);
#pragma unroll
    for (int o = 32; o; o >>= 1) m = fmaxf(m, __shfl_xor(m, o));
    float ssum = 0.f;
    for (int k = lane; k < deg; k += 64) ssum += __expf(csr_e[base + k] - m);
#pragma unroll
    for (int o = 32; o; o >>= 1) ssum += __shfl_xor(ssum, o);
    const float inv = 1.0f / ssum;
    for (int k = 0; k < deg; ++k) {
      const int sk = csr_src[base + k];
      const float pk = __expf(csr_e[base + k] - m) * inv;
      acc += pk * xv[(size_t)sk * OUT_F + lane];
    }
  }
  out[(size_t)node * OUT_F + lane] = acc;
}

extern "C" void kernel_launch(void* const* d_in, const int* in_sizes, int n_in,
                              void* d_out, int out_size, void* d_ws, size_t ws_size,
                              hipStream_t stream) {
  const float* x  = (const float*)d_in[0];
  const float* Wv = (const float*)d_in[1];
  const float* bv = (const float*)d_in[2];
  const float* wq = (const float*)d_in[3];
  const float* bq = (const float*)d_in[4];
  const float* wk = (const float*)d_in[5];
  const float* bk = (const float*)d_in[6];
  const int* src  = (const int*)d_in[7];
  const int* dst  = (const int*)d_in[8];
  float* out = (float*)d_out;

  // workspace layout (4-byte words):
  // xv[NN*64] el[NN] er[NN] cnt[NN] cursor[NN] off[NN] csr_src[NE] csr_e[NE] wvt[IN_F*OUT_F/2]
  float* xv = (float*)d_ws;
  float* el = xv + (size_t)NN * 64;
  float* er = el + NN;
  int* cnt = (int*)(er + NN);
  int* cursor = cnt + NN;          // cnt+cursor adjacent -> one memset
  int* off = cursor + NN;
  int* csr_src = off + NN;
  float* csr_e = (float*)(csr_src + NE);
  short* wvt = (short*)(csr_e + NE);

  hipMemsetAsync(cnt, 0, (size_t)NN * 2 * sizeof(int), stream);  // cnt + cursor

  prep_w<<<(IN_F * OUT_F + 255) / 256, 256, 0, stream>>>(Wv, wvt);
  node_transform<<<(NN + 63) / 64, 256, 0, stream>>>(x, wvt, bv, wq, bq, wk, bk, xv, el, er);
  count_deg<<<(NE + 255) / 256, 256, 0, stream>>>(dst, cnt);
  scan_kernel<<<1, 1024, 0, stream>>>(cnt, off);
  scatter_edges<<<(NE + 255) / 256, 256, 0, stream>>>(el, er, src, dst, off, cursor,
                                                      csr_src, csr_e);
  node_aggregate<<<(NN + 3) / 4, 256, 0, stream>>>(xv, cnt, off, csr_src, csr_e, out);
}

// Round 4
// 245.550 us; speedup vs baseline: 2.9022x; 1.6180x over previous
//
#include <hip/hip_runtime.h>
#include <hip/hip_bf16.h>

#define NN 100000
#define NE 1600000
#define IN_F 128
#define OUT_F 64

typedef __attribute__((ext_vector_type(8))) short bf16x8;
typedef __attribute__((ext_vector_type(4))) float f32x4;

__device__ __forceinline__ short f2bf(float f) {
  unsigned u = __float_as_uint(f);
  unsigned r = (u + 0x7fffu + ((u >> 16) & 1u)) >> 16;  // RNE
  return (short)r;
}

// ---------------- Kernel 0: wvt[j][k] = bf16(Wv[k][j])  (64 x 128 transposed)
__global__ __launch_bounds__(256) void prep_w(
    const float* __restrict__ Wv, short* __restrict__ wvt) {
  const int i = blockIdx.x * 256 + threadIdx.x;
  if (i >= IN_F * OUT_F) return;
  const int j = i >> 7, k = i & 127;
  wvt[i] = f2bf(Wv[k * OUT_F + j]);
}

// ---------------- Kernel 1: xv = x@Wv + bv ; el = xv.wq + bq ; er = xv.wk + bk
// MFMA 16x16x32 bf16. Block = 4 waves, each wave owns 16 nodes x 64 feats.
__global__ __launch_bounds__(256) void node_transform(
    const float* __restrict__ x, const short* __restrict__ wvt,
    const float* __restrict__ bv, const float* __restrict__ wq,
    const float* __restrict__ bq, const float* __restrict__ wk,
    const float* __restrict__ bk,
    float* __restrict__ xv, float* __restrict__ el, float* __restrict__ er) {
  const int wave = threadIdx.x >> 6, lane = threadIdx.x & 63;
  const int node0 = blockIdx.x * 64 + wave * 16;
  const int j15 = lane & 15, g = lane >> 4;
  const int kb = g * 8;

  int row = node0 + j15;
  if (row >= NN) row = NN - 1;
  const float* xr = x + (size_t)row * IN_F;
  bf16x8 a[4];
#pragma unroll
  for (int kt = 0; kt < 4; ++kt) {
    const float4 f0 = *(const float4*)(xr + kt * 32 + kb);
    const float4 f1 = *(const float4*)(xr + kt * 32 + kb + 4);
    bf16x8 t;
    t[0] = f2bf(f0.x); t[1] = f2bf(f0.y); t[2] = f2bf(f0.z); t[3] = f2bf(f0.w);
    t[4] = f2bf(f1.x); t[5] = f2bf(f1.y); t[6] = f2bf(f1.z); t[7] = f2bf(f1.w);
    a[kt] = t;
  }

  bf16x8 b[16];
#pragma unroll
  for (int nt = 0; nt < 4; ++nt)
#pragma unroll
    for (int kt = 0; kt < 4; ++kt)
      b[nt * 4 + kt] = *(const bf16x8*)(wvt + (size_t)(nt * 16 + j15) * IN_F + kt * 32 + kb);

  f32x4 acc[4];
#pragma unroll
  for (int nt = 0; nt < 4; ++nt) acc[nt] = (f32x4){0.f, 0.f, 0.f, 0.f};
#pragma unroll
  for (int nt = 0; nt < 4; ++nt)
#pragma unroll
    for (int kt = 0; kt < 4; ++kt)
      acc[nt] = __builtin_amdgcn_mfma_f32_16x16x32_bf16(a[kt], b[nt * 4 + kt], acc[nt], 0, 0, 0);

  float bvl[4], wql[4], wkl[4];
#pragma unroll
  for (int nt = 0; nt < 4; ++nt) {
    bvl[nt] = bv[nt * 16 + j15];
    wql[nt] = wq[nt * 16 + j15];
    wkl[nt] = wk[nt * 16 + j15];
  }
  const float bq0 = bq[0], bk0 = bk[0];

#pragma unroll
  for (int r = 0; r < 4; ++r) {
    const int node = node0 + g * 4 + r;
    float pq = 0.f, pk = 0.f;
#pragma unroll
    for (int nt = 0; nt < 4; ++nt) {
      const float v = acc[nt][r] + bvl[nt];
      if (node < NN) xv[(size_t)node * OUT_F + nt * 16 + j15] = v;
      pq += v * wql[nt];
      pk += v * wkl[nt];
    }
#pragma unroll
    for (int o = 1; o < 16; o <<= 1) {
      pq += __shfl_xor(pq, o);
      pk += __shfl_xor(pk, o);
    }
    if (j15 == 0 && node < NN) {
      el[node] = pq + bq0;
      er[node] = pk + bk0;
    }
  }
}

// ---------------- Kernel 2: per-dst in-degree histogram
__global__ __launch_bounds__(256) void count_deg(
    const int* __restrict__ dst, int* __restrict__ cnt) {
  const int i = blockIdx.x * 256 + threadIdx.x;
  if (i >= NE) return;
  atomicAdd(&cnt[dst[i]], 1);
}

// ---------------- Scan (3 dispatches). Block = 256 thr x 4 elems = 1024 elems.
#define SCAN_NB 98  // 98*1024 >= 100000

__global__ __launch_bounds__(256) void scan_local(
    const int* __restrict__ cnt, int* __restrict__ off, int* __restrict__ part) {
  __shared__ int sWave[4];
  const int t = threadIdx.x, wave = t >> 6, lane = t & 63;
  const int idx0 = blockIdx.x * 1024 + t * 4;
  int c0 = 0, c1 = 0, c2 = 0, c3 = 0;
  if (idx0 + 3 < NN) {
    const int4 v = *(const int4*)(cnt + idx0);
    c0 = v.x; c1 = v.y; c2 = v.z; c3 = v.w;
  } else {
    if (idx0 + 0 < NN) c0 = cnt[idx0 + 0];
    if (idx0 + 1 < NN) c1 = cnt[idx0 + 1];
    if (idx0 + 2 < NN) c2 = cnt[idx0 + 2];
    if (idx0 + 3 < NN) c3 = cnt[idx0 + 3];
  }
  const int tsum = c0 + c1 + c2 + c3;
  int incl = tsum;
#pragma unroll
  for (int o = 1; o < 64; o <<= 1) {
    const int v = __shfl_up(incl, o);
    if (lane >= o) incl += v;
  }
  if (lane == 63) sWave[wave] = incl;
  __syncthreads();
  int wbase = 0;
#pragma unroll
  for (int w = 0; w < 4; ++w) wbase += (w < wave) ? sWave[w] : 0;
  int base = wbase + incl - tsum;
  if (idx0 + 3 < NN) {
    *(int4*)(off + idx0) = (int4){base, base + c0, base + c0 + c1, base + c0 + c1 + c2};
  } else {
    if (idx0 + 0 < NN) off[idx0 + 0] = base;
    if (idx0 + 1 < NN) off[idx0 + 1] = base + c0;
    if (idx0 + 2 < NN) off[idx0 + 2] = base + c0 + c1;
    if (idx0 + 3 < NN) off[idx0 + 3] = base + c0 + c1 + c2;
  }
  if (t == 0) part[blockIdx.x] = 0;  // placeholder, fixed below
  __syncthreads();
  if (t == 255) part[blockIdx.x] = wbase + incl;
}

__global__ __launch_bounds__(128) void scan_part(int* __restrict__ part) {
  __shared__ int sp[128];
  const int t = threadIdx.x;
  sp[t] = (t < SCAN_NB) ? part[t] : 0;
  __syncthreads();
  for (int o = 1; o < 128; o <<= 1) {
    const int v = (t >= o) ? sp[t - o] : 0;
    __syncthreads();
    sp[t] += v;
    __syncthreads();
  }
  if (t < SCAN_NB) part[t] = (t > 0) ? sp[t - 1] : 0;  // exclusive
}

__global__ __launch_bounds__(256) void add_base(
    int* __restrict__ off, const int* __restrict__ part) {
  const int idx0 = blockIdx.x * 1024 + threadIdx.x * 4;
  const int b = part[blockIdx.x];
  if (idx0 + 3 < NN) {
    int4 v = *(const int4*)(off + idx0);
    v.x += b; v.y += b; v.z += b; v.w += b;
    *(int4*)(off + idx0) = v;
  } else {
    if (idx0 + 0 < NN) off[idx0 + 0] += b;
    if (idx0 + 1 < NN) off[idx0 + 1] += b;
    if (idx0 + 2 < NN) off[idx0 + 2] += b;
    if (idx0 + 3 < NN) off[idx0 + 3] += b;
  }
}

// ---------------- Kernel 4: scatter edges into CSR slots; fuse leaky-relu score
__global__ __launch_bounds__(256) void scatter_edges(
    const float* __restrict__ el, const float* __restrict__ er,
    const int* __restrict__ src, const int* __restrict__ dst,
    const int* __restrict__ off, int* __restrict__ cursor,
    int* __restrict__ csr_src, float* __restrict__ csr_e) {
  const int i = blockIdx.x * 256 + threadIdx.x;
  if (i >= NE) return;
  const int s = src[i], d = dst[i];
  float e = el[s] + er[d];
  e = e > 0.f ? e : 0.2f * e;
  const int pos = atomicAdd(&cursor[d], 1);
  const int idx = off[d] + pos;
  csr_src[idx] = s;
  csr_e[idx] = e;
}

// ---------------- Kernel 5: per-node fused softmax + weighted gather-sum
__global__ __launch_bounds__(256) void node_aggregate(
    const float* __restrict__ xv, const int* __restrict__ cnt,
    const int* __restrict__ off, const int* __restrict__ csr_src,
    const float* __restrict__ csr_e, float* __restrict__ out) {
  const int wave = threadIdx.x >> 6, lane = threadIdx.x & 63;
  const int node = blockIdx.x * 4 + wave;
  if (node >= NN) return;
  const int deg = cnt[node];
  const int base = off[node];

  float acc = 0.f;
  if (deg <= 64) {
    const bool valid = lane < deg;
    float e = valid ? csr_e[base + lane] : -3.0e38f;
    int s = valid ? csr_src[base + lane] : 0;
    float m = e;
#pragma unroll
    for (int o = 32; o; o >>= 1) m = fmaxf(m, __shfl_xor(m, o));
    float p = valid ? __expf(e - m) : 0.f;
    float t = p;
#pragma unroll
    for (int o = 32; o; o >>= 1) t += __shfl_xor(t, o);
    p *= (deg > 0) ? (1.0f / t) : 0.f;

    int k = 0;
    for (; k + 4 <= deg; k += 4) {
      const int s0 = __shfl(s, k), s1 = __shfl(s, k + 1);
      const int s2 = __shfl(s, k + 2), s3 = __shfl(s, k + 3);
      const float p0 = __shfl(p, k), p1 = __shfl(p, k + 1);
      const float p2 = __shfl(p, k + 2), p3 = __shfl(p, k + 3);
      const float v0 = xv[(size_t)s0 * OUT_F + lane];
      const float v1 = xv[(size_t)s1 * OUT_F + lane];
      const float v2 = xv[(size_t)s2 * OUT_F + lane];
      const float v3 = xv[(size_t)s3 * OUT_F + lane];
      acc += p0 * v0 + p1 * v1 + p2 * v2 + p3 * v3;
    }
    for (; k < deg; ++k) {
      const int sk = __shfl(s, k);
      const float pk = __shfl(p, k);
      acc += pk * xv[(size_t)sk * OUT_F + lane];
    }
  } else {
    float m = -3.0e38f;
    for (int k = lane; k < deg; k += 64) m = fmaxf(m, csr_e[base + k]);
#pragma unroll
    for (int o = 32; o; o >>= 1) m = fmaxf(m, __shfl_xor(m, o));
    float ssum = 0.f;
    for (int k = lane; k < deg; k += 64) ssum += __expf(csr_e[base + k] - m);
#pragma unroll
    for (int o = 32; o; o >>= 1) ssum += __shfl_xor(ssum, o);
    const float inv = 1.0f / ssum;
    for (int k = 0; k < deg; ++k) {
      const int sk = csr_src[base + k];
      const float pk = __expf(csr_e[base + k] - m) * inv;
      acc += pk * xv[(size_t)sk * OUT_F + lane];
    }
  }
  out[(size_t)node * OUT_F + lane] = acc;
}

extern "C" void kernel_launch(void* const* d_in, const int* in_sizes, int n_in,
                              void* d_out, int out_size, void* d_ws, size_t ws_size,
                              hipStream_t stream) {
  const float* x  = (const float*)d_in[0];
  const float* Wv = (const float*)d_in[1];
  const float* bv = (const float*)d_in[2];
  const float* wq = (const float*)d_in[3];
  const float* bq = (const float*)d_in[4];
  const float* wk = (const float*)d_in[5];
  const float* bk = (const float*)d_in[6];
  const int* src  = (const int*)d_in[7];
  const int* dst  = (const int*)d_in[8];
  float* out = (float*)d_out;

  // workspace layout (4-byte words):
  // xv[NN*64] el[NN] er[NN] cnt[NN] cursor[NN] off[NN] csr_src[NE] csr_e[NE]
  // wvt[IN_F*OUT_F/2 words] part[SCAN_NB]
  float* xv = (float*)d_ws;
  float* el = xv + (size_t)NN * 64;
  float* er = el + NN;
  int* cnt = (int*)(er + NN);
  int* cursor = cnt + NN;          // cnt+cursor adjacent -> one memset
  int* off = cursor + NN;
  int* csr_src = off + NN;
  float* csr_e = (float*)(csr_src + NE);
  short* wvt = (short*)(csr_e + NE);
  int* part = (int*)(wvt + IN_F * OUT_F);

  hipMemsetAsync(cnt, 0, (size_t)NN * 2 * sizeof(int), stream);  // cnt + cursor

  prep_w<<<(IN_F * OUT_F + 255) / 256, 256, 0, stream>>>(Wv, wvt);
  node_transform<<<(NN + 63) / 64, 256, 0, stream>>>(x, wvt, bv, wq, bq, wk, bk, xv, el, er);
  count_deg<<<(NE + 255) / 256, 256, 0, stream>>>(dst, cnt);
  scan_local<<<SCAN_NB, 256, 0, stream>>>(cnt, off, part);
  scan_part<<<1, 128, 0, stream>>>(part);
  add_base<<<SCAN_NB, 256, 0, stream>>>(off, part);
  scatter_edges<<<(NE + 255) / 256, 256, 0, stream>>>(el, er, src, dst, off, cursor,
                                                      csr_src, csr_e);
  node_aggregate<<<(NN + 3) / 4, 256, 0, stream>>>(xv, cnt, off, csr_src, csr_e, out);
}